// Round 7
// baseline (620.010 us; speedup 1.0000x reference)
//
#include <hip/hip_runtime.h>

typedef unsigned short u16;
typedef __attribute__((ext_vector_type(8))) short short8;
typedef __attribute__((ext_vector_type(4))) float fx4;
typedef __attribute__((ext_vector_type(4))) int ix4;
typedef __attribute__((ext_vector_type(4))) unsigned short ux4;

__device__ __forceinline__ float bf2f(u16 h) {
  union { unsigned u; float f; } a; a.u = ((unsigned)h) << 16; return a.f;
}
__device__ __forceinline__ u16 f2bf(float f) {
  union { float f; unsigned u; } a; a.f = f;
  unsigned u = a.u;
  return (u16)((u + 0x7FFFu + ((u >> 16) & 1u)) >> 16);  // RNE
}

// async global->LDS, 16B per lane. LDS dest must be wave-uniform base + lane*16.
__device__ __forceinline__ void gl_lds(const u16* g, u16* l) {
  __builtin_amdgcn_global_load_lds(
      (const __attribute__((address_space(1))) unsigned*)g,
      (__attribute__((address_space(3))) unsigned*)l, 16, 0, 0);
}

constexpr int S_LEN = 2048;
constexpr int DM = 2048;
constexpr int HD = 128;
constexpr int NH = 16;
constexpr float NEG = -1.0e9f;
constexpr float SC2 = 0.08838834764831845f * 1.4426950408889634f;  // 1/sqrt(128)*log2(e)

// ---------------------------------------------------------------------------
// fp32 -> bf16 bulk convert (memory-bound)
// ---------------------------------------------------------------------------
__global__ __launch_bounds__(256)
void cvt_kernel(const float* __restrict__ in, u16* __restrict__ out)
{
  int idx = blockIdx.x * 256 + threadIdx.x;
  fx4 v = *(const fx4*)&in[(size_t)idx * 4];
  ux4 pk;
  pk[0] = f2bf(v[0]); pk[1] = f2bf(v[1]); pk[2] = f2bf(v[2]); pk[3] = f2bf(v[3]);
  *(ux4*)&out[(size_t)idx * 4] = pk;
}

// ---------------------------------------------------------------------------
// GEMM: C[M,N] = A[M,K] @ W[N,K]^T + bias (bias fp32)
// MODE 0: fp32 out to o0;  MODE 1: QKV scatter bf16 (o0=Q, o1=K, o2=V^T)
// AB16/WB16: source dtype of A/W. bf16 sources use global_load_lds(16B) staging.
// LDS tiles chunk-XOR-swizzled: LDS(row, cc) holds global(row, cc ^ ((row>>1)&3)).
// ---------------------------------------------------------------------------
template<int M, int N, int K, int MODE, bool AB16, bool WB16>
__global__ __launch_bounds__(256)
void gemm_bt(const void* __restrict__ Av, const void* __restrict__ Wv,
             const float* __restrict__ bias,
             void* __restrict__ o0, u16* __restrict__ o1, u16* __restrict__ o2)
{
  constexpr int BK = 32;
  __shared__ u16 la[128 * BK];
  __shared__ u16 lb[128 * BK];
  const int tid  = threadIdx.x;
  const int lane = tid & 63;
  const int wv   = tid >> 6;
  const int wm   = wv >> 1, wn = wv & 1;
  const int quad = lane >> 4, l16 = lane & 15;
  const int m0 = blockIdx.y * 128, n0 = blockIdx.x * 128;
  const int csw = (quad ^ ((l16 >> 1) & 3)) * 8;   // swizzled chunk for frag reads

  fx4 acc[4][4] = {};

  for (int k0 = 0; k0 < K; k0 += BK) {
    __syncthreads();
    if constexpr (AB16) {
      const u16* ap = (const u16*)Av + (size_t)m0 * K + k0;
      #pragma unroll
      for (int i = 0; i < 2; ++i) {
        int c = i * 256 + tid, row = c >> 2, cc = c & 3;
        int g = cc ^ ((row >> 1) & 3);
        gl_lds(ap + (size_t)row * K + g * 8, &la[c * 8]);
      }
    } else {
      const float* ap = (const float*)Av + (size_t)m0 * K + k0;
      #pragma unroll
      for (int i = 0; i < 2; ++i) {
        int c = i * 256 + tid, row = c >> 2, cc = c & 3;
        fx4 v0 = *(const fx4*)&ap[(size_t)row * K + cc * 8];
        fx4 v1 = *(const fx4*)&ap[(size_t)row * K + cc * 8 + 4];
        ux4 p0, p1;
        p0[0]=f2bf(v0[0]); p0[1]=f2bf(v0[1]); p0[2]=f2bf(v0[2]); p0[3]=f2bf(v0[3]);
        p1[0]=f2bf(v1[0]); p1[1]=f2bf(v1[1]); p1[2]=f2bf(v1[2]); p1[3]=f2bf(v1[3]);
        int s = cc ^ ((row >> 1) & 3);
        *(ux4*)&la[row * BK + s * 8]     = p0;
        *(ux4*)&la[row * BK + s * 8 + 4] = p1;
      }
    }
    if constexpr (WB16) {
      const u16* wp = (const u16*)Wv + (size_t)n0 * K + k0;
      #pragma unroll
      for (int i = 0; i < 2; ++i) {
        int c = i * 256 + tid, row = c >> 2, cc = c & 3;
        int g = cc ^ ((row >> 1) & 3);
        gl_lds(wp + (size_t)row * K + g * 8, &lb[c * 8]);
      }
    } else {
      const float* wp = (const float*)Wv + (size_t)n0 * K + k0;
      #pragma unroll
      for (int i = 0; i < 2; ++i) {
        int c = i * 256 + tid, row = c >> 2, cc = c & 3;
        fx4 v0 = *(const fx4*)&wp[(size_t)row * K + cc * 8];
        fx4 v1 = *(const fx4*)&wp[(size_t)row * K + cc * 8 + 4];
        ux4 p0, p1;
        p0[0]=f2bf(v0[0]); p0[1]=f2bf(v0[1]); p0[2]=f2bf(v0[2]); p0[3]=f2bf(v0[3]);
        p1[0]=f2bf(v1[0]); p1[1]=f2bf(v1[1]); p1[2]=f2bf(v1[2]); p1[3]=f2bf(v1[3]);
        int s = cc ^ ((row >> 1) & 3);
        *(ux4*)&lb[row * BK + s * 8]     = p0;
        *(ux4*)&lb[row * BK + s * 8 + 4] = p1;
      }
    }
    __syncthreads();
    short8 af[4], bfg[4];
    #pragma unroll
    for (int t = 0; t < 4; ++t) {
      af[t]  = *(const short8*)&la[(wm * 64 + t * 16 + l16) * BK + csw];
      bfg[t] = *(const short8*)&lb[(wn * 64 + t * 16 + l16) * BK + csw];
    }
    #pragma unroll
    for (int mt = 0; mt < 4; ++mt)
      #pragma unroll
      for (int nt = 0; nt < 4; ++nt)
        acc[mt][nt] = __builtin_amdgcn_mfma_f32_16x16x32_bf16(af[mt], bfg[nt], acc[mt][nt], 0, 0, 0);
  }

  if constexpr (MODE == 0) {
    float* of = (float*)o0;
    #pragma unroll
    for (int nt = 0; nt < 4; ++nt) {
      int col = n0 + wn * 64 + nt * 16 + l16;
      float bz = bias[col];
      #pragma unroll
      for (int mt = 0; mt < 4; ++mt) {
        int row = m0 + wm * 64 + mt * 16 + quad * 4;
        #pragma unroll
        for (int r = 0; r < 4; ++r)
          of[(size_t)(row + r) * N + col] = acc[mt][nt][r] + bz;
      }
    }
  } else {
    u16* q0 = (u16*)o0;
    const int which = n0 >> 11;
    const int head  = (n0 >> 7) & 15;
    const int b     = m0 >> 11;
    const int bh    = b * NH + head;
    #pragma unroll
    for (int nt = 0; nt < 4; ++nt) {
      int dcol = wn * 64 + nt * 16 + l16;
      float bz = bias[n0 + dcol];
      #pragma unroll
      for (int mt = 0; mt < 4; ++mt) {
        int srow = (m0 & (S_LEN - 1)) + wm * 64 + mt * 16 + quad * 4;
        if (which == 2) {
          ux4 pk;
          #pragma unroll
          for (int r = 0; r < 4; ++r) pk[r] = f2bf(acc[mt][nt][r] + bz);
          *(ux4*)&o2[((size_t)bh * HD + dcol) * S_LEN + srow] = pk;  // V^T
        } else {
          u16* buf = (which == 0) ? q0 : o1;
          size_t base = ((size_t)bh * S_LEN + srow) * HD + dcol;
          #pragma unroll
          for (int r = 0; r < 4; ++r)
            buf[base + (size_t)r * HD] = f2bf(acc[mt][nt][r] + bz);
        }
      }
    }
  }
}

// ---------------------------------------------------------------------------
// RoPE in place on Q and K
// ---------------------------------------------------------------------------
__global__ __launch_bounds__(256)
void rope_kernel(u16* __restrict__ qbuf, u16* __restrict__ kbuf)
{
  int idx = blockIdx.x * 256 + threadIdx.x;
  int i  = idx & 63;
  int s  = (idx >> 6) & (S_LEN - 1);
  int bh = idx >> 17;
  float invf = exp2f((float)i * -0.20762050594f);
  float ang = (float)s * invf;
  float sn = sinf(ang), cs = cosf(ang);
  size_t base = ((size_t)bh * S_LEN + s) * HD + i;
  float q1 = bf2f(qbuf[base]), q2 = bf2f(qbuf[base + 64]);
  qbuf[base]      = f2bf(q1 * cs - q2 * sn);
  qbuf[base + 64] = f2bf(q2 * cs + q1 * sn);
  float k1 = bf2f(kbuf[base]), k2 = bf2f(kbuf[base + 64]);
  kbuf[base]      = f2bf(k1 * cs - k2 * sn);
  kbuf[base + 64] = f2bf(k2 * cs + k1 * sn);
}

// ---------------------------------------------------------------------------
// Online-softmax tile step: scale, mask, row-max/sum (16-lane reduce),
// rescale O, write P (bf16) to per-wave LDS in A-layout order. In-place on s.
// ---------------------------------------------------------------------------
__device__ __forceinline__ void soft_tile(fx4 s[4], float* m, float* l, fx4* o,
                                          u16* lp, bool mask, int rb, int k0,
                                          int l16, int quad)
{
  #pragma unroll
  for (int snt = 0; snt < 4; ++snt)
    #pragma unroll
    for (int r = 0; r < 4; ++r) {
      float v = s[snt][r] * SC2;
      if (mask && (k0 + snt * 16 + l16 > rb + r)) v = NEG;
      s[snt][r] = v;
    }
  #pragma unroll
  for (int r = 0; r < 4; ++r) {
    float mx = fmaxf(fmaxf(s[0][r], s[1][r]), fmaxf(s[2][r], s[3][r]));
    #pragma unroll
    for (int off = 1; off < 16; off <<= 1) mx = fmaxf(mx, __shfl_xor(mx, off, 64));
    float mn = fmaxf(m[r], mx);
    float al = exp2f(m[r] - mn);
    m[r] = mn;
    float rs = 0.f;
    #pragma unroll
    for (int snt = 0; snt < 4; ++snt) {
      float pz = exp2f(s[snt][r] - mn);
      s[snt][r] = pz;
      rs += pz;
    }
    #pragma unroll
    for (int off = 1; off < 16; off <<= 1) rs += __shfl_xor(rs, off, 64);
    l[r] = l[r] * al + rs;
    #pragma unroll
    for (int nd = 0; nd < 8; ++nd) o[nd][r] *= al;
  }
  #pragma unroll
  for (int snt = 0; snt < 4; ++snt)
    #pragma unroll
    for (int r = 0; r < 4; ++r)
      lp[(quad * 4 + r) * 72 + snt * 16 + l16] = f2bf(s[snt][r]);
}

// ---------------------------------------------------------------------------
// Flash attention (causal), paired q-tiles (p, 31-p) -> uniform 33 MFMA-iters.
// Grid (16, 32), 4 waves, each wave 16 rows of EACH tile (32 q-rows/wave):
// K/V frags read from LDS once, reused by both tiles (halves LDS B/FLOP vs
// single-tile). launch_bounds(256,1) -> allocator may use up to 256 VGPRs
// (live state ~190; round-5 spill was the 128-reg cap).
// ---------------------------------------------------------------------------
__global__ __launch_bounds__(256, 1)
void attn_kernel(const u16* __restrict__ qbuf, const u16* __restrict__ kbuf,
                 const u16* __restrict__ vtbuf, u16* __restrict__ ctx)
{
  __shared__ u16 lk[64 * 128];     // K tile  [key][d],  swizzled chunks
  __shared__ u16 lv[128 * 64];     // V^T tile [d][key], swizzled chunks
  __shared__ u16 lph[4][16 * 72];  // per-wave P (hi tile)
  __shared__ u16 lpl[4][16 * 72];  // per-wave P (lo tile)
  const int tid = threadIdx.x, lane = tid & 63, wv = tid >> 6;
  const int quad = lane >> 4, l16 = lane & 15;
  const int p = blockIdx.x, bh = blockIdx.y;
  const int qt_lo = p, qt_hi = 31 - p;
  const int head = bh & 15, b = bh >> 4;
  const int s8 = l16 & 7;          // frag-read swizzle index

  short8 qh[4], ql[4];
  {
    const size_t bh_ = ((size_t)bh * S_LEN + qt_hi * 64 + wv * 16 + l16) * HD;
    const size_t bl_ = ((size_t)bh * S_LEN + qt_lo * 64 + wv * 16 + l16) * HD;
    #pragma unroll
    for (int kd = 0; kd < 4; ++kd) {
      qh[kd] = *(const short8*)&qbuf[bh_ + kd * 32 + quad * 8];
      ql[kd] = *(const short8*)&qbuf[bl_ + kd * 32 + quad * 8];
    }
  }

  fx4 oh[8] = {}, ol[8] = {};
  float mh[4], lh[4], ml[4], ll[4];
  #pragma unroll
  for (int r = 0; r < 4; ++r) { mh[r] = NEG; lh[r] = 0.f; ml[r] = NEG; ll[r] = 0.f; }
  const int rb_hi = qt_hi * 64 + wv * 16 + quad * 4;
  const int rb_lo = qt_lo * 64 + wv * 16 + quad * 4;

  for (int kt = 0; kt <= qt_hi; ++kt) {
    const int k0 = kt * 64;
    const bool dlo = (kt <= qt_lo);
    __syncthreads();
    {
      const u16* kg = kbuf + ((size_t)bh * S_LEN + k0) * HD;
      const u16* vg = vtbuf + (size_t)bh * HD * S_LEN + k0;
      #pragma unroll
      for (int i = 0; i < 4; ++i) {           // K tile: 64 rows x 16 chunks
        int c = i * 256 + tid;
        int row = c >> 4, cc = c & 15;
        int g = cc ^ (row & 7);
        gl_lds(kg + (size_t)row * HD + g * 8, &lk[c * 8]);
      }
      #pragma unroll
      for (int i = 0; i < 4; ++i) {           // V^T tile: 128 rows x 8 chunks
        int c = i * 256 + tid;
        int row = c >> 3, cc = c & 7;
        int g = cc ^ (row & 7);
        gl_lds(vg + (size_t)row * S_LEN + g * 8, &lv[c * 8]);
      }
    }
    __syncthreads();

    // QK^T for both tiles, K-frag loaded once
    fx4 sh[4] = {}, sl[4] = {};
    #pragma unroll
    for (int snt = 0; snt < 4; ++snt) {
      #pragma unroll
      for (int kd = 0; kd < 4; ++kd) {
        int cc = (kd * 4 + quad) ^ s8;
        short8 kf = *(const short8*)&lk[(snt * 16 + l16) * 128 + cc * 8];
        sh[snt] = __builtin_amdgcn_mfma_f32_16x16x32_bf16(qh[kd], kf, sh[snt], 0, 0, 0);
        if (dlo)
          sl[snt] = __builtin_amdgcn_mfma_f32_16x16x32_bf16(ql[kd], kf, sl[snt], 0, 0, 0);
      }
    }

    soft_tile(sh, mh, lh, oh, lph[wv], kt == qt_hi, rb_hi, k0, l16, quad);
    if (dlo) soft_tile(sl, ml, ll, ol, lpl[wv], kt == qt_lo, rb_lo, k0, l16, quad);

    // PV for both tiles, V-frag loaded once
    #pragma unroll
    for (int kk = 0; kk < 2; ++kk) {
      short8 ph = *(const short8*)&lph[wv][l16 * 72 + kk * 32 + quad * 8];
      short8 pl = *(const short8*)&lpl[wv][l16 * 72 + kk * 32 + quad * 8];
      #pragma unroll
      for (int nd = 0; nd < 8; ++nd) {
        int cc = (kk * 4 + quad) ^ s8;
        short8 vf = *(const short8*)&lv[(nd * 16 + l16) * 64 + cc * 8];
        oh[nd] = __builtin_amdgcn_mfma_f32_16x16x32_bf16(ph, vf, oh[nd], 0, 0, 0);
        if (dlo)
          ol[nd] = __builtin_amdgcn_mfma_f32_16x16x32_bf16(pl, vf, ol[nd], 0, 0, 0);
      }
    }
  }

  #pragma unroll
  for (int r = 0; r < 4; ++r) {
    float ih = 1.f / lh[r], il = 1.f / ll[r];
    size_t mrh = (size_t)b * S_LEN + qt_hi * 64 + wv * 16 + quad * 4 + r;
    size_t mrl = (size_t)b * S_LEN + qt_lo * 64 + wv * 16 + quad * 4 + r;
    #pragma unroll
    for (int nd = 0; nd < 8; ++nd) {
      ctx[mrh * DM + head * HD + nd * 16 + l16] = f2bf(oh[nd][r] * ih);
      ctx[mrl * DM + head * HD + nd * 16 + l16] = f2bf(ol[nd][r] * il);
    }
  }
}

// ---------------------------------------------------------------------------
extern "C" void kernel_launch(void* const* d_in, const int* in_sizes, int n_in,
                              void* d_out, int out_size, void* d_ws, size_t ws_size,
                              hipStream_t stream)
{
  const float* x    = (const float*)d_in[0];
  const float* Wqkv = (const float*)d_in[2];
  const float* bqkv = (const float*)d_in[3];
  const float* Wout = (const float*)d_in[4];
  const float* bout = (const float*)d_in[5];
  float* out = (float*)d_out;

  constexpr size_t XB_E = (size_t)4096 * 2048;   // 8.39M elems
  constexpr size_t WQ_E = (size_t)6144 * 2048;
  constexpr size_t WO_E = (size_t)2048 * 2048;
  constexpr size_t NEED = (XB_E + WQ_E + WO_E + 3 * XB_E) * 2;  // ~101 MB

  if (ws_size >= NEED) {
    u16* xb  = (u16*)d_ws;
    u16* wqb = xb + XB_E;
    u16* wob = wqb + WQ_E;
    u16* qb  = wob + WO_E;
    u16* kb  = qb + XB_E;
    u16* vb  = kb + XB_E;
    u16* ctx = xb;                 // xb dead after QKV GEMM; reuse for ctx

    cvt_kernel<<<dim3(XB_E / 1024), 256, 0, stream>>>(x, xb);
    cvt_kernel<<<dim3(WQ_E / 1024), 256, 0, stream>>>(Wqkv, wqb);
    cvt_kernel<<<dim3(WO_E / 1024), 256, 0, stream>>>(Wout, wob);
    gemm_bt<4096, 6144, 2048, 1, true, true><<<dim3(48, 32), 256, 0, stream>>>(
        xb, wqb, bqkv, qb, kb, vb);
    rope_kernel<<<dim3(16384), 256, 0, stream>>>(qb, kb);
    attn_kernel<<<dim3(16, 32), 256, 0, stream>>>(qb, kb, vb, ctx);
    gemm_bt<4096, 2048, 2048, 0, true, true><<<dim3(16, 32), 256, 0, stream>>>(
        ctx, wob, bout, out, nullptr, nullptr);
  } else {
    // fallback: 48 MiB ws, fused fp32->bf16 staging in GEMMs, ctx in d_out
    u16* qb = (u16*)d_ws;
    u16* kb = qb + XB_E;
    u16* vb = kb + XB_E;
    u16* ctx = (u16*)d_out;
    float* tmpo = (float*)d_ws;   // over dead qb/kb at out-proj time

    gemm_bt<4096, 6144, 2048, 1, false, false><<<dim3(48, 32), 256, 0, stream>>>(
        x, Wqkv, bqkv, qb, kb, vb);
    rope_kernel<<<dim3(16384), 256, 0, stream>>>(qb, kb);
    attn_kernel<<<dim3(16, 32), 256, 0, stream>>>(qb, kb, vb, ctx);
    gemm_bt<4096, 2048, 2048, 0, true, false><<<dim3(16, 32), 256, 0, stream>>>(
        ctx, Wout, bout, tmpo, nullptr, nullptr);
    hipMemcpyAsync(out, tmpo, (size_t)out_size * sizeof(float),
                   hipMemcpyDeviceToDevice, stream);
  }
}

// Round 8
// 445.248 us; speedup vs baseline: 1.3925x; 1.3925x over previous
//
#include <hip/hip_runtime.h>

typedef unsigned short u16;
typedef __attribute__((ext_vector_type(8))) short short8;
typedef __attribute__((ext_vector_type(4))) float fx4;
typedef __attribute__((ext_vector_type(4))) int ix4;
typedef __attribute__((ext_vector_type(4))) unsigned short ux4;

__device__ __forceinline__ float bf2f(u16 h) {
  union { unsigned u; float f; } a; a.u = ((unsigned)h) << 16; return a.f;
}
__device__ __forceinline__ u16 f2bf(float f) {
  union { float f; unsigned u; } a; a.f = f;
  unsigned u = a.u;
  return (u16)((u + 0x7FFFu + ((u >> 16) & 1u)) >> 16);  // RNE
}

// async global->LDS, 16B per lane. LDS dest must be wave-uniform base + lane*16.
__device__ __forceinline__ void gl_lds(const u16* g, u16* l) {
  __builtin_amdgcn_global_load_lds(
      (const __attribute__((address_space(1))) unsigned*)g,
      (__attribute__((address_space(3))) unsigned*)l, 16, 0, 0);
}

constexpr int S_LEN = 2048;
constexpr int DM = 2048;
constexpr int HD = 128;
constexpr int NH = 16;
constexpr float NEG = -1.0e9f;
constexpr float SC2 = 0.08838834764831845f * 1.4426950408889634f;  // 1/sqrt(128)*log2(e)

// ---------------------------------------------------------------------------
// fp32 -> bf16 bulk convert (memory-bound)
// ---------------------------------------------------------------------------
__global__ __launch_bounds__(256)
void cvt_kernel(const float* __restrict__ in, u16* __restrict__ out)
{
  int idx = blockIdx.x * 256 + threadIdx.x;
  fx4 v = *(const fx4*)&in[(size_t)idx * 4];
  ux4 pk;
  pk[0] = f2bf(v[0]); pk[1] = f2bf(v[1]); pk[2] = f2bf(v[2]); pk[3] = f2bf(v[3]);
  *(ux4*)&out[(size_t)idx * 4] = pk;
}

// ---------------------------------------------------------------------------
// GEMM: C[M,N] = A[M,K] @ W[N,K]^T + bias (bias fp32)
// MODE 0: fp32 out to o0;  MODE 1: QKV scatter bf16 (o0=Q, o1=K, o2=V^T)
// AB16/WB16: source dtype of A/W. bf16 sources use global_load_lds(16B) staging.
// LDS tiles chunk-XOR-swizzled: LDS(row, cc) holds global(row, cc ^ ((row>>1)&3)).
// ---------------------------------------------------------------------------
template<int M, int N, int K, int MODE, bool AB16, bool WB16>
__global__ __launch_bounds__(256)
void gemm_bt(const void* __restrict__ Av, const void* __restrict__ Wv,
             const float* __restrict__ bias,
             void* __restrict__ o0, u16* __restrict__ o1, u16* __restrict__ o2)
{
  constexpr int BK = 32;
  __shared__ u16 la[128 * BK];
  __shared__ u16 lb[128 * BK];
  const int tid  = threadIdx.x;
  const int lane = tid & 63;
  const int wv   = tid >> 6;
  const int wm   = wv >> 1, wn = wv & 1;
  const int quad = lane >> 4, l16 = lane & 15;
  const int m0 = blockIdx.y * 128, n0 = blockIdx.x * 128;
  const int csw = (quad ^ ((l16 >> 1) & 3)) * 8;   // swizzled chunk for frag reads

  fx4 acc[4][4] = {};

  for (int k0 = 0; k0 < K; k0 += BK) {
    __syncthreads();
    if constexpr (AB16) {
      const u16* ap = (const u16*)Av + (size_t)m0 * K + k0;
      #pragma unroll
      for (int i = 0; i < 2; ++i) {
        int c = i * 256 + tid, row = c >> 2, cc = c & 3;
        int g = cc ^ ((row >> 1) & 3);
        gl_lds(ap + (size_t)row * K + g * 8, &la[c * 8]);
      }
    } else {
      const float* ap = (const float*)Av + (size_t)m0 * K + k0;
      #pragma unroll
      for (int i = 0; i < 2; ++i) {
        int c = i * 256 + tid, row = c >> 2, cc = c & 3;
        fx4 v0 = *(const fx4*)&ap[(size_t)row * K + cc * 8];
        fx4 v1 = *(const fx4*)&ap[(size_t)row * K + cc * 8 + 4];
        ux4 p0, p1;
        p0[0]=f2bf(v0[0]); p0[1]=f2bf(v0[1]); p0[2]=f2bf(v0[2]); p0[3]=f2bf(v0[3]);
        p1[0]=f2bf(v1[0]); p1[1]=f2bf(v1[1]); p1[2]=f2bf(v1[2]); p1[3]=f2bf(v1[3]);
        int s = cc ^ ((row >> 1) & 3);
        *(ux4*)&la[row * BK + s * 8]     = p0;
        *(ux4*)&la[row * BK + s * 8 + 4] = p1;
      }
    }
    if constexpr (WB16) {
      const u16* wp = (const u16*)Wv + (size_t)n0 * K + k0;
      #pragma unroll
      for (int i = 0; i < 2; ++i) {
        int c = i * 256 + tid, row = c >> 2, cc = c & 3;
        int g = cc ^ ((row >> 1) & 3);
        gl_lds(wp + (size_t)row * K + g * 8, &lb[c * 8]);
      }
    } else {
      const float* wp = (const float*)Wv + (size_t)n0 * K + k0;
      #pragma unroll
      for (int i = 0; i < 2; ++i) {
        int c = i * 256 + tid, row = c >> 2, cc = c & 3;
        fx4 v0 = *(const fx4*)&wp[(size_t)row * K + cc * 8];
        fx4 v1 = *(const fx4*)&wp[(size_t)row * K + cc * 8 + 4];
        ux4 p0, p1;
        p0[0]=f2bf(v0[0]); p0[1]=f2bf(v0[1]); p0[2]=f2bf(v0[2]); p0[3]=f2bf(v0[3]);
        p1[0]=f2bf(v1[0]); p1[1]=f2bf(v1[1]); p1[2]=f2bf(v1[2]); p1[3]=f2bf(v1[3]);
        int s = cc ^ ((row >> 1) & 3);
        *(ux4*)&lb[row * BK + s * 8]     = p0;
        *(ux4*)&lb[row * BK + s * 8 + 4] = p1;
      }
    }
    __syncthreads();
    short8 af[4], bfg[4];
    #pragma unroll
    for (int t = 0; t < 4; ++t) {
      af[t]  = *(const short8*)&la[(wm * 64 + t * 16 + l16) * BK + csw];
      bfg[t] = *(const short8*)&lb[(wn * 64 + t * 16 + l16) * BK + csw];
    }
    #pragma unroll
    for (int mt = 0; mt < 4; ++mt)
      #pragma unroll
      for (int nt = 0; nt < 4; ++nt)
        acc[mt][nt] = __builtin_amdgcn_mfma_f32_16x16x32_bf16(af[mt], bfg[nt], acc[mt][nt], 0, 0, 0);
  }

  if constexpr (MODE == 0) {
    float* of = (float*)o0;
    #pragma unroll
    for (int nt = 0; nt < 4; ++nt) {
      int col = n0 + wn * 64 + nt * 16 + l16;
      float bz = bias[col];
      #pragma unroll
      for (int mt = 0; mt < 4; ++mt) {
        int row = m0 + wm * 64 + mt * 16 + quad * 4;
        #pragma unroll
        for (int r = 0; r < 4; ++r)
          of[(size_t)(row + r) * N + col] = acc[mt][nt][r] + bz;
      }
    }
  } else {
    u16* q0 = (u16*)o0;
    const int which = n0 >> 11;
    const int head  = (n0 >> 7) & 15;
    const int b     = m0 >> 11;
    const int bh    = b * NH + head;
    #pragma unroll
    for (int nt = 0; nt < 4; ++nt) {
      int dcol = wn * 64 + nt * 16 + l16;
      float bz = bias[n0 + dcol];
      #pragma unroll
      for (int mt = 0; mt < 4; ++mt) {
        int srow = (m0 & (S_LEN - 1)) + wm * 64 + mt * 16 + quad * 4;
        if (which == 2) {
          ux4 pk;
          #pragma unroll
          for (int r = 0; r < 4; ++r) pk[r] = f2bf(acc[mt][nt][r] + bz);
          *(ux4*)&o2[((size_t)bh * HD + dcol) * S_LEN + srow] = pk;  // V^T
        } else {
          u16* buf = (which == 0) ? q0 : o1;
          size_t base = ((size_t)bh * S_LEN + srow) * HD + dcol;
          #pragma unroll
          for (int r = 0; r < 4; ++r)
            buf[base + (size_t)r * HD] = f2bf(acc[mt][nt][r] + bz);
        }
      }
    }
  }
}

// ---------------------------------------------------------------------------
// RoPE in place on Q and K
// ---------------------------------------------------------------------------
__global__ __launch_bounds__(256)
void rope_kernel(u16* __restrict__ qbuf, u16* __restrict__ kbuf)
{
  int idx = blockIdx.x * 256 + threadIdx.x;
  int i  = idx & 63;
  int s  = (idx >> 6) & (S_LEN - 1);
  int bh = idx >> 17;
  float invf = exp2f((float)i * -0.20762050594f);
  float ang = (float)s * invf;
  float sn = sinf(ang), cs = cosf(ang);
  size_t base = ((size_t)bh * S_LEN + s) * HD + i;
  float q1 = bf2f(qbuf[base]), q2 = bf2f(qbuf[base + 64]);
  qbuf[base]      = f2bf(q1 * cs - q2 * sn);
  qbuf[base + 64] = f2bf(q2 * cs + q1 * sn);
  float k1 = bf2f(kbuf[base]), k2 = bf2f(kbuf[base + 64]);
  kbuf[base]      = f2bf(k1 * cs - k2 * sn);
  kbuf[base + 64] = f2bf(k2 * cs + k1 * sn);
}

// ---------------------------------------------------------------------------
// Transposed online-softmax tile step. S^T in C-layout: lane owns q-row=l16,
// 16 keys = snt*16 + quad*4 + r in registers. Row reduce = in-register tree
// + 2 shuffles (xor 16/32 across quads). m/l/alpha are per-lane scalars.
// P written as [q][key] bf16, 4 x ds_write_b64 per lane.
// ---------------------------------------------------------------------------
__device__ __forceinline__ void soft_tile_t(fx4 s[4], float& m, float& l, fx4* o,
                                            u16* lp, bool mask, int qrow, int k0,
                                            int l16, int quad)
{
  #pragma unroll
  for (int snt = 0; snt < 4; ++snt)
    #pragma unroll
    for (int r = 0; r < 4; ++r) {
      float v = s[snt][r] * SC2;
      if (mask && (k0 + snt * 16 + quad * 4 + r > qrow)) v = NEG;
      s[snt][r] = v;
    }
  float mx = s[0][0];
  #pragma unroll
  for (int snt = 0; snt < 4; ++snt)
    #pragma unroll
    for (int r = 0; r < 4; ++r) mx = fmaxf(mx, s[snt][r]);
  mx = fmaxf(mx, __shfl_xor(mx, 16, 64));
  mx = fmaxf(mx, __shfl_xor(mx, 32, 64));
  float mn = fmaxf(m, mx);
  float al = exp2f(m - mn);
  m = mn;
  float rs = 0.f;
  #pragma unroll
  for (int snt = 0; snt < 4; ++snt)
    #pragma unroll
    for (int r = 0; r < 4; ++r) {
      float pz = exp2f(s[snt][r] - mn);
      s[snt][r] = pz;
      rs += pz;
    }
  rs += __shfl_xor(rs, 16, 64);
  rs += __shfl_xor(rs, 32, 64);
  l = l * al + rs;
  #pragma unroll
  for (int nd = 0; nd < 8; ++nd)
    #pragma unroll
    for (int r = 0; r < 4; ++r) o[nd][r] *= al;
  #pragma unroll
  for (int snt = 0; snt < 4; ++snt) {
    ux4 pk;
    #pragma unroll
    for (int r = 0; r < 4; ++r) pk[r] = f2bf(s[snt][r]);
    *(ux4*)&lp[l16 * 72 + snt * 16 + quad * 4] = pk;   // 8B write
  }
}

// ---------------------------------------------------------------------------
// Flash attention (causal), paired q-tiles (p, 31-p), TRANSPOSED pipeline:
// S^T = K·Q^T (A=K, B=Q)  and  O^T = V^T·P^T (A=V^T, B=P) — same fragment
// reads as the direct form, operands swapped. Softmax is per-lane-scalar.
// Grid (16, 32), 4 waves; K/V LDS tiles shared by all waves and both tiles.
// ---------------------------------------------------------------------------
__global__ __launch_bounds__(256, 2)
void attn_kernel(const u16* __restrict__ qbuf, const u16* __restrict__ kbuf,
                 const u16* __restrict__ vtbuf, u16* __restrict__ ctx)
{
  __shared__ u16 lk[64 * 128];     // K tile  [key][d],  swizzled chunks
  __shared__ u16 lv[128 * 64];     // V^T tile [d][key], swizzled chunks
  __shared__ u16 lph[4][16 * 72];  // per-wave P (hi tile) [q][key]
  __shared__ u16 lpl[4][16 * 72];  // per-wave P (lo tile)
  const int tid = threadIdx.x, lane = tid & 63, wv = tid >> 6;
  const int quad = lane >> 4, l16 = lane & 15;
  const int p = blockIdx.x, bh = blockIdx.y;
  const int qt_lo = p, qt_hi = 31 - p;
  const int head = bh & 15, b = bh >> 4;
  const int s8 = l16 & 7;          // frag-read swizzle index

  short8 qh[4], ql[4];
  {
    const size_t bh_ = ((size_t)bh * S_LEN + qt_hi * 64 + wv * 16 + l16) * HD;
    const size_t bl_ = ((size_t)bh * S_LEN + qt_lo * 64 + wv * 16 + l16) * HD;
    #pragma unroll
    for (int kd = 0; kd < 4; ++kd) {
      qh[kd] = *(const short8*)&qbuf[bh_ + kd * 32 + quad * 8];
      ql[kd] = *(const short8*)&qbuf[bl_ + kd * 32 + quad * 8];
    }
  }

  fx4 oh[8] = {}, ol[8] = {};
  float mh = NEG, lh = 0.f, ml = NEG, llo = 0.f;
  const int qrow_hi = qt_hi * 64 + wv * 16 + l16;
  const int qrow_lo = qt_lo * 64 + wv * 16 + l16;

  for (int kt = 0; kt <= qt_hi; ++kt) {
    const int k0 = kt * 64;
    const bool dlo = (kt <= qt_lo);
    __syncthreads();
    {
      const u16* kg = kbuf + ((size_t)bh * S_LEN + k0) * HD;
      const u16* vg = vtbuf + (size_t)bh * HD * S_LEN + k0;
      #pragma unroll
      for (int i = 0; i < 4; ++i) {           // K tile: 64 rows x 16 chunks
        int c = i * 256 + tid;
        int row = c >> 4, cc = c & 15;
        int g = cc ^ (row & 7);
        gl_lds(kg + (size_t)row * HD + g * 8, &lk[c * 8]);
      }
      #pragma unroll
      for (int i = 0; i < 4; ++i) {           // V^T tile: 128 rows x 8 chunks
        int c = i * 256 + tid;
        int row = c >> 3, cc = c & 7;
        int g = cc ^ (row & 7);
        gl_lds(vg + (size_t)row * S_LEN + g * 8, &lv[c * 8]);
      }
    }
    __syncthreads();

    // S^T = K·Q^T for both tiles; K-frag (A operand) loaded once
    fx4 sh[4] = {}, sl[4] = {};
    #pragma unroll
    for (int snt = 0; snt < 4; ++snt) {
      #pragma unroll
      for (int kd = 0; kd < 4; ++kd) {
        int cc = (kd * 4 + quad) ^ s8;
        short8 kf = *(const short8*)&lk[(snt * 16 + l16) * 128 + cc * 8];
        sh[snt] = __builtin_amdgcn_mfma_f32_16x16x32_bf16(kf, qh[kd], sh[snt], 0, 0, 0);
        if (dlo)
          sl[snt] = __builtin_amdgcn_mfma_f32_16x16x32_bf16(kf, ql[kd], sl[snt], 0, 0, 0);
      }
    }

    soft_tile_t(sh, mh, lh, oh, lph[wv], kt == qt_hi, qrow_hi, k0, l16, quad);
    if (dlo) soft_tile_t(sl, ml, llo, ol, lpl[wv], kt == qt_lo, qrow_lo, k0, l16, quad);

    // O^T += V^T·P^T for both tiles; V-frag (A operand) loaded once
    #pragma unroll
    for (int kk = 0; kk < 2; ++kk) {
      short8 ph = *(const short8*)&lph[wv][l16 * 72 + kk * 32 + quad * 8];
      short8 pl = *(const short8*)&lpl[wv][l16 * 72 + kk * 32 + quad * 8];
      #pragma unroll
      for (int nd = 0; nd < 8; ++nd) {
        int cc = (kk * 4 + quad) ^ s8;
        short8 vf = *(const short8*)&lv[(nd * 16 + l16) * 64 + cc * 8];
        oh[nd] = __builtin_amdgcn_mfma_f32_16x16x32_bf16(vf, ph, oh[nd], 0, 0, 0);
        if (dlo)
          ol[nd] = __builtin_amdgcn_mfma_f32_16x16x32_bf16(vf, pl, ol[nd], 0, 0, 0);
      }
    }
  }

  // O^T regs: lane q=l16, d = nd*16 + quad*4 + r  -> 8B packed stores
  {
    float ih = 1.f / lh, il = 1.f / llo;
    size_t rh = ((size_t)b * S_LEN + qt_hi * 64 + wv * 16 + l16) * DM + head * HD;
    size_t rl = ((size_t)b * S_LEN + qt_lo * 64 + wv * 16 + l16) * DM + head * HD;
    #pragma unroll
    for (int nd = 0; nd < 8; ++nd) {
      ux4 ph, pl;
      #pragma unroll
      for (int r = 0; r < 4; ++r) {
        ph[r] = f2bf(oh[nd][r] * ih);
        pl[r] = f2bf(ol[nd][r] * il);
      }
      *(ux4*)&ctx[rh + nd * 16 + quad * 4] = ph;
      *(ux4*)&ctx[rl + nd * 16 + quad * 4] = pl;
    }
  }
}

// ---------------------------------------------------------------------------
extern "C" void kernel_launch(void* const* d_in, const int* in_sizes, int n_in,
                              void* d_out, int out_size, void* d_ws, size_t ws_size,
                              hipStream_t stream)
{
  const float* x    = (const float*)d_in[0];
  const float* Wqkv = (const float*)d_in[2];
  const float* bqkv = (const float*)d_in[3];
  const float* Wout = (const float*)d_in[4];
  const float* bout = (const float*)d_in[5];
  float* out = (float*)d_out;

  constexpr size_t XB_E = (size_t)4096 * 2048;   // 8.39M elems
  constexpr size_t WQ_E = (size_t)6144 * 2048;
  constexpr size_t WO_E = (size_t)2048 * 2048;
  constexpr size_t NEED = (XB_E + WQ_E + WO_E + 3 * XB_E) * 2;  // ~101 MB

  if (ws_size >= NEED) {
    u16* xb  = (u16*)d_ws;
    u16* wqb = xb + XB_E;
    u16* wob = wqb + WQ_E;
    u16* qb  = wob + WO_E;
    u16* kb  = qb + XB_E;
    u16* vb  = kb + XB_E;
    u16* ctx = xb;                 // xb dead after QKV GEMM; reuse for ctx

    cvt_kernel<<<dim3(XB_E / 1024), 256, 0, stream>>>(x, xb);
    cvt_kernel<<<dim3(WQ_E / 1024), 256, 0, stream>>>(Wqkv, wqb);
    cvt_kernel<<<dim3(WO_E / 1024), 256, 0, stream>>>(Wout, wob);
    gemm_bt<4096, 6144, 2048, 1, true, true><<<dim3(48, 32), 256, 0, stream>>>(
        xb, wqb, bqkv, qb, kb, vb);
    rope_kernel<<<dim3(16384), 256, 0, stream>>>(qb, kb);
    attn_kernel<<<dim3(16, 32), 256, 0, stream>>>(qb, kb, vb, ctx);
    gemm_bt<4096, 2048, 2048, 0, true, true><<<dim3(16, 32), 256, 0, stream>>>(
        ctx, wob, bout, out, nullptr, nullptr);
  } else {
    // fallback: 48 MiB ws, fused fp32->bf16 staging in GEMMs, ctx in d_out
    u16* qb = (u16*)d_ws;
    u16* kb = qb + XB_E;
    u16* vb = kb + XB_E;
    u16* ctx = (u16*)d_out;
    float* tmpo = (float*)d_ws;   // over dead qb/kb at out-proj time

    gemm_bt<4096, 6144, 2048, 1, false, false><<<dim3(48, 32), 256, 0, stream>>>(
        x, Wqkv, bqkv, qb, kb, vb);
    rope_kernel<<<dim3(16384), 256, 0, stream>>>(qb, kb);
    attn_kernel<<<dim3(16, 32), 256, 0, stream>>>(qb, kb, vb, ctx);
    gemm_bt<4096, 2048, 2048, 0, true, false><<<dim3(16, 32), 256, 0, stream>>>(
        ctx, Wout, bout, tmpo, nullptr, nullptr);
    hipMemcpyAsync(out, tmpo, (size_t)out_size * sizeof(float),
                   hipMemcpyDeviceToDevice, stream);
  }
}

// Round 9
// 417.811 us; speedup vs baseline: 1.4839x; 1.0657x over previous
//
#include <hip/hip_runtime.h>

typedef unsigned short u16;
typedef __attribute__((ext_vector_type(8))) short short8;
typedef __attribute__((ext_vector_type(4))) float fx4;
typedef __attribute__((ext_vector_type(4))) int ix4;
typedef __attribute__((ext_vector_type(4))) unsigned short ux4;

__device__ __forceinline__ float bf2f(u16 h) {
  union { unsigned u; float f; } a; a.u = ((unsigned)h) << 16; return a.f;
}
__device__ __forceinline__ u16 f2bf(float f) {
  union { float f; unsigned u; } a; a.f = f;
  unsigned u = a.u;
  return (u16)((u + 0x7FFFu + ((u >> 16) & 1u)) >> 16);  // RNE
}

// async global->LDS, 16B per lane. LDS dest must be wave-uniform base + lane*16.
__device__ __forceinline__ void gl_lds(const u16* g, u16* l) {
  __builtin_amdgcn_global_load_lds(
      (const __attribute__((address_space(1))) unsigned*)g,
      (__attribute__((address_space(3))) unsigned*)l, 16, 0, 0);
}

constexpr int S_LEN = 2048;
constexpr int DM = 2048;
constexpr int HD = 128;
constexpr int NH = 16;
constexpr float NEG = -1.0e9f;
constexpr float SC2 = 0.08838834764831845f * 1.4426950408889634f;  // 1/sqrt(128)*log2(e)

// ---------------------------------------------------------------------------
// fp32 -> bf16 bulk convert (memory-bound)
// ---------------------------------------------------------------------------
__global__ __launch_bounds__(256)
void cvt_kernel(const float* __restrict__ in, u16* __restrict__ out)
{
  int idx = blockIdx.x * 256 + threadIdx.x;
  fx4 v = *(const fx4*)&in[(size_t)idx * 4];
  ux4 pk;
  pk[0] = f2bf(v[0]); pk[1] = f2bf(v[1]); pk[2] = f2bf(v[2]); pk[3] = f2bf(v[3]);
  *(ux4*)&out[(size_t)idx * 4] = pk;
}

// ---------------------------------------------------------------------------
// GEMM: C[M,N] = A[M,K] @ W[N,K]^T + bias (bias fp32)
// MODE 0: fp32 out to o0;  MODE 1: QKV scatter bf16 (o0=Q, o1=K, o2=V^T)
//         with RoPE fused into the Q/K epilogue.
// Wave wn owns column pairs: ncol(nt) = (nt&2)*32 + wn*32 + (nt&1)*16, so the
// RoPE pair (i, i+64) is acc[mt][nt] / acc[mt][nt+2] — in-register rotation.
// BK=64, 8-chunk XOR swizzle: LDS(row,cc) = global(row, cc ^ (row&7)).
// ---------------------------------------------------------------------------
template<int M, int N, int K, int MODE, bool AB16, bool WB16>
__global__ __launch_bounds__(256)
void gemm_bt(const void* __restrict__ Av, const void* __restrict__ Wv,
             const float* __restrict__ bias,
             void* __restrict__ o0, u16* __restrict__ o1, u16* __restrict__ o2)
{
  constexpr int BK = 64;
  __shared__ u16 la[128 * BK];
  __shared__ u16 lb[128 * BK];
  const int tid  = threadIdx.x;
  const int lane = tid & 63;
  const int wv   = tid >> 6;
  const int wm   = wv >> 1, wn = wv & 1;
  const int quad = lane >> 4, l16 = lane & 15;
  const int m0 = blockIdx.y * 128, n0 = blockIdx.x * 128;
  const int sw = l16 & 7;                     // frag-read swizzle (row&7 = l16&7)

  fx4 acc[4][4] = {};

  for (int k0 = 0; k0 < K; k0 += BK) {
    __syncthreads();
    if constexpr (AB16) {
      const u16* ap = (const u16*)Av + (size_t)m0 * K + k0;
      #pragma unroll
      for (int i = 0; i < 4; ++i) {
        int c = i * 256 + tid, row = c >> 3, cc = c & 7;
        int g = cc ^ (row & 7);
        gl_lds(ap + (size_t)row * K + g * 8, &la[c * 8]);
      }
    } else {
      const float* ap = (const float*)Av + (size_t)m0 * K + k0;
      #pragma unroll
      for (int i = 0; i < 4; ++i) {
        int c = i * 256 + tid, row = c >> 3, cc = c & 7;
        fx4 v0 = *(const fx4*)&ap[(size_t)row * K + cc * 8];
        fx4 v1 = *(const fx4*)&ap[(size_t)row * K + cc * 8 + 4];
        ux4 p0, p1;
        p0[0]=f2bf(v0[0]); p0[1]=f2bf(v0[1]); p0[2]=f2bf(v0[2]); p0[3]=f2bf(v0[3]);
        p1[0]=f2bf(v1[0]); p1[1]=f2bf(v1[1]); p1[2]=f2bf(v1[2]); p1[3]=f2bf(v1[3]);
        int s = cc ^ (row & 7);
        *(ux4*)&la[row * BK + s * 8]     = p0;
        *(ux4*)&la[row * BK + s * 8 + 4] = p1;
      }
    }
    if constexpr (WB16) {
      const u16* wp = (const u16*)Wv + (size_t)n0 * K + k0;
      #pragma unroll
      for (int i = 0; i < 4; ++i) {
        int c = i * 256 + tid, row = c >> 3, cc = c & 7;
        int g = cc ^ (row & 7);
        gl_lds(wp + (size_t)row * K + g * 8, &lb[c * 8]);
      }
    } else {
      const float* wp = (const float*)Wv + (size_t)n0 * K + k0;
      #pragma unroll
      for (int i = 0; i < 4; ++i) {
        int c = i * 256 + tid, row = c >> 3, cc = c & 7;
        fx4 v0 = *(const fx4*)&wp[(size_t)row * K + cc * 8];
        fx4 v1 = *(const fx4*)&wp[(size_t)row * K + cc * 8 + 4];
        ux4 p0, p1;
        p0[0]=f2bf(v0[0]); p0[1]=f2bf(v0[1]); p0[2]=f2bf(v0[2]); p0[3]=f2bf(v0[3]);
        p1[0]=f2bf(v1[0]); p1[1]=f2bf(v1[1]); p1[2]=f2bf(v1[2]); p1[3]=f2bf(v1[3]);
        int s = cc ^ (row & 7);
        *(ux4*)&lb[row * BK + s * 8]     = p0;
        *(ux4*)&lb[row * BK + s * 8 + 4] = p1;
      }
    }
    __syncthreads();
    #pragma unroll
    for (int ks = 0; ks < 2; ++ks) {
      short8 af[4], bfg[4];
      #pragma unroll
      for (int t = 0; t < 4; ++t) {
        int arow = wm * 64 + t * 16 + l16;
        int brow = (t & 2) * 32 + wn * 32 + (t & 1) * 16 + l16;
        int cc = (ks * 4 + quad) ^ sw;
        af[t]  = *(const short8*)&la[arow * BK + cc * 8];
        bfg[t] = *(const short8*)&lb[brow * BK + cc * 8];
      }
      #pragma unroll
      for (int mt = 0; mt < 4; ++mt)
        #pragma unroll
        for (int nt = 0; nt < 4; ++nt)
          acc[mt][nt] = __builtin_amdgcn_mfma_f32_16x16x32_bf16(af[mt], bfg[nt], acc[mt][nt], 0, 0, 0);
    }
  }

  if constexpr (MODE == 0) {
    float* of = (float*)o0;
    #pragma unroll
    for (int nt = 0; nt < 4; ++nt) {
      int col = n0 + (nt & 2) * 32 + wn * 32 + (nt & 1) * 16 + l16;
      float bz = bias[col];
      #pragma unroll
      for (int mt = 0; mt < 4; ++mt) {
        int row = m0 + wm * 64 + mt * 16 + quad * 4;
        #pragma unroll
        for (int r = 0; r < 4; ++r)
          of[(size_t)(row + r) * N + col] = acc[mt][nt][r] + bz;
      }
    }
  } else {
    const int which = n0 >> 11;
    const int head  = (n0 >> 7) & 15;
    const int b     = m0 >> 11;
    const int bh    = b * NH + head;
    if (which == 2) {
      #pragma unroll
      for (int nt = 0; nt < 4; ++nt) {
        int dcol = (nt & 2) * 32 + wn * 32 + (nt & 1) * 16 + l16;
        float bz = bias[n0 + dcol];
        #pragma unroll
        for (int mt = 0; mt < 4; ++mt) {
          int srow = (m0 & (S_LEN - 1)) + wm * 64 + mt * 16 + quad * 4;
          ux4 pk;
          #pragma unroll
          for (int r = 0; r < 4; ++r) pk[r] = f2bf(acc[mt][nt][r] + bz);
          *(ux4*)&o2[((size_t)bh * HD + dcol) * S_LEN + srow] = pk;  // V^T
        }
      }
    } else {
      // Q or K with fused RoPE: pair (i, i+64) = acc[..][nt] / acc[..][nt+2]
      u16* buf = (which == 0) ? (u16*)o0 : o1;
      #pragma unroll
      for (int nt = 0; nt < 2; ++nt) {
        int i = wn * 32 + nt * 16 + l16;            // 0..63
        float invf = exp2f((float)i * -0.20762050594f);  // 10000^(-i/64)
        float bz1 = bias[n0 + i];
        float bz2 = bias[n0 + i + 64];
        #pragma unroll
        for (int mt = 0; mt < 4; ++mt) {
          int srow = (m0 & (S_LEN - 1)) + wm * 64 + mt * 16 + quad * 4;
          size_t base = ((size_t)bh * S_LEN + srow) * HD + i;
          #pragma unroll
          for (int r = 0; r < 4; ++r) {
            float ang = (float)(srow + r) * invf;
            float sn, cs;
            sincosf(ang, &sn, &cs);
            float v1 = acc[mt][nt][r] + bz1;
            float v2 = acc[mt][nt + 2][r] + bz2;
            buf[base + (size_t)r * HD]      = f2bf(v1 * cs - v2 * sn);
            buf[base + (size_t)r * HD + 64] = f2bf(v2 * cs + v1 * sn);
          }
        }
      }
    }
  }
}

// ---------------------------------------------------------------------------
// Transposed online-softmax tile step. S^T in C-layout: lane owns q-row=l16,
// 16 keys = snt*16 + quad*4 + r in registers. Row reduce = in-register tree
// + 2 shuffles. m/l/alpha are per-lane scalars. P -> LDS [q][key], 8B writes.
// ---------------------------------------------------------------------------
__device__ __forceinline__ void soft_tile_t(fx4 s[4], float& m, float& l, fx4* o,
                                            u16* lp, bool mask, int qrow, int k0,
                                            int l16, int quad)
{
  #pragma unroll
  for (int snt = 0; snt < 4; ++snt)
    #pragma unroll
    for (int r = 0; r < 4; ++r) {
      float v = s[snt][r] * SC2;
      if (mask && (k0 + snt * 16 + quad * 4 + r > qrow)) v = NEG;
      s[snt][r] = v;
    }
  float mx = s[0][0];
  #pragma unroll
  for (int snt = 0; snt < 4; ++snt)
    #pragma unroll
    for (int r = 0; r < 4; ++r) mx = fmaxf(mx, s[snt][r]);
  mx = fmaxf(mx, __shfl_xor(mx, 16, 64));
  mx = fmaxf(mx, __shfl_xor(mx, 32, 64));
  float mn = fmaxf(m, mx);
  float al = exp2f(m - mn);
  m = mn;
  float rs = 0.f;
  #pragma unroll
  for (int snt = 0; snt < 4; ++snt)
    #pragma unroll
    for (int r = 0; r < 4; ++r) {
      float pz = exp2f(s[snt][r] - mn);
      s[snt][r] = pz;
      rs += pz;
    }
  rs += __shfl_xor(rs, 16, 64);
  rs += __shfl_xor(rs, 32, 64);
  l = l * al + rs;
  #pragma unroll
  for (int nd = 0; nd < 8; ++nd)
    #pragma unroll
    for (int r = 0; r < 4; ++r) o[nd][r] *= al;
  #pragma unroll
  for (int snt = 0; snt < 4; ++snt) {
    ux4 pk;
    #pragma unroll
    for (int r = 0; r < 4; ++r) pk[r] = f2bf(s[snt][r]);
    *(ux4*)&lp[l16 * 72 + snt * 16 + quad * 4] = pk;   // 8B write
  }
}

// ---------------------------------------------------------------------------
// Flash attention (causal), paired q-tiles (p, 31-p), transposed pipeline:
// S^T = K·Q^T and O^T = V^T·P^T. Per-lane-scalar softmax. Grid (16, 32),
// 4 waves; K/V LDS tiles shared by all waves and both tiles.
// ---------------------------------------------------------------------------
__global__ __launch_bounds__(256, 2)
void attn_kernel(const u16* __restrict__ qbuf, const u16* __restrict__ kbuf,
                 const u16* __restrict__ vtbuf, u16* __restrict__ ctx)
{
  __shared__ u16 lk[64 * 128];     // K tile  [key][d],  swizzled chunks
  __shared__ u16 lv[128 * 64];     // V^T tile [d][key], swizzled chunks
  __shared__ u16 lph[4][16 * 72];  // per-wave P (hi tile) [q][key]
  __shared__ u16 lpl[4][16 * 72];  // per-wave P (lo tile)
  const int tid = threadIdx.x, lane = tid & 63, wv = tid >> 6;
  const int quad = lane >> 4, l16 = lane & 15;
  const int p = blockIdx.x, bh = blockIdx.y;
  const int qt_lo = p, qt_hi = 31 - p;
  const int head = bh & 15, b = bh >> 4;
  const int s8 = l16 & 7;          // frag-read swizzle index

  short8 qh[4], ql[4];
  {
    const size_t bh_ = ((size_t)bh * S_LEN + qt_hi * 64 + wv * 16 + l16) * HD;
    const size_t bl_ = ((size_t)bh * S_LEN + qt_lo * 64 + wv * 16 + l16) * HD;
    #pragma unroll
    for (int kd = 0; kd < 4; ++kd) {
      qh[kd] = *(const short8*)&qbuf[bh_ + kd * 32 + quad * 8];
      ql[kd] = *(const short8*)&qbuf[bl_ + kd * 32 + quad * 8];
    }
  }

  fx4 oh[8] = {}, ol[8] = {};
  float mh = NEG, lh = 0.f, ml = NEG, llo = 0.f;
  const int qrow_hi = qt_hi * 64 + wv * 16 + l16;
  const int qrow_lo = qt_lo * 64 + wv * 16 + l16;

  for (int kt = 0; kt <= qt_hi; ++kt) {
    const int k0 = kt * 64;
    const bool dlo = (kt <= qt_lo);
    __syncthreads();
    {
      const u16* kg = kbuf + ((size_t)bh * S_LEN + k0) * HD;
      const u16* vg = vtbuf + (size_t)bh * HD * S_LEN + k0;
      #pragma unroll
      for (int i = 0; i < 4; ++i) {           // K tile: 64 rows x 16 chunks
        int c = i * 256 + tid;
        int row = c >> 4, cc = c & 15;
        int g = cc ^ (row & 7);
        gl_lds(kg + (size_t)row * HD + g * 8, &lk[c * 8]);
      }
      #pragma unroll
      for (int i = 0; i < 4; ++i) {           // V^T tile: 128 rows x 8 chunks
        int c = i * 256 + tid;
        int row = c >> 3, cc = c & 7;
        int g = cc ^ (row & 7);
        gl_lds(vg + (size_t)row * S_LEN + g * 8, &lv[c * 8]);
      }
    }
    __syncthreads();

    // S^T = K·Q^T for both tiles; K-frag (A operand) loaded once
    fx4 sh[4] = {}, sl[4] = {};
    #pragma unroll
    for (int snt = 0; snt < 4; ++snt) {
      #pragma unroll
      for (int kd = 0; kd < 4; ++kd) {
        int cc = (kd * 4 + quad) ^ s8;
        short8 kf = *(const short8*)&lk[(snt * 16 + l16) * 128 + cc * 8];
        sh[snt] = __builtin_amdgcn_mfma_f32_16x16x32_bf16(kf, qh[kd], sh[snt], 0, 0, 0);
        if (dlo)
          sl[snt] = __builtin_amdgcn_mfma_f32_16x16x32_bf16(kf, ql[kd], sl[snt], 0, 0, 0);
      }
    }

    soft_tile_t(sh, mh, lh, oh, lph[wv], kt == qt_hi, qrow_hi, k0, l16, quad);
    if (dlo) soft_tile_t(sl, ml, llo, ol, lpl[wv], kt == qt_lo, qrow_lo, k0, l16, quad);

    // O^T += V^T·P^T for both tiles; V-frag (A operand) loaded once
    #pragma unroll
    for (int kk = 0; kk < 2; ++kk) {
      short8 ph = *(const short8*)&lph[wv][l16 * 72 + kk * 32 + quad * 8];
      short8 pl = *(const short8*)&lpl[wv][l16 * 72 + kk * 32 + quad * 8];
      #pragma unroll
      for (int nd = 0; nd < 8; ++nd) {
        int cc = (kk * 4 + quad) ^ s8;
        short8 vf = *(const short8*)&lv[(nd * 16 + l16) * 64 + cc * 8];
        oh[nd] = __builtin_amdgcn_mfma_f32_16x16x32_bf16(vf, ph, oh[nd], 0, 0, 0);
        if (dlo)
          ol[nd] = __builtin_amdgcn_mfma_f32_16x16x32_bf16(vf, pl, ol[nd], 0, 0, 0);
      }
    }
  }

  // O^T regs: lane q=l16, d = nd*16 + quad*4 + r  -> 8B packed stores
  {
    float ih = 1.f / lh, il = 1.f / llo;
    size_t rh = ((size_t)b * S_LEN + qt_hi * 64 + wv * 16 + l16) * DM + head * HD;
    size_t rl = ((size_t)b * S_LEN + qt_lo * 64 + wv * 16 + l16) * DM + head * HD;
    #pragma unroll
    for (int nd = 0; nd < 8; ++nd) {
      ux4 ph, pl;
      #pragma unroll
      for (int r = 0; r < 4; ++r) {
        ph[r] = f2bf(oh[nd][r] * ih);
        pl[r] = f2bf(ol[nd][r] * il);
      }
      *(ux4*)&ctx[rh + nd * 16 + quad * 4] = ph;
      *(ux4*)&ctx[rl + nd * 16 + quad * 4] = pl;
    }
  }
}

// ---------------------------------------------------------------------------
extern "C" void kernel_launch(void* const* d_in, const int* in_sizes, int n_in,
                              void* d_out, int out_size, void* d_ws, size_t ws_size,
                              hipStream_t stream)
{
  const float* x    = (const float*)d_in[0];
  const float* Wqkv = (const float*)d_in[2];
  const float* bqkv = (const float*)d_in[3];
  const float* Wout = (const float*)d_in[4];
  const float* bout = (const float*)d_in[5];
  float* out = (float*)d_out;

  constexpr size_t XB_E = (size_t)4096 * 2048;   // 8.39M elems
  constexpr size_t WQ_E = (size_t)6144 * 2048;
  constexpr size_t WO_E = (size_t)2048 * 2048;
  constexpr size_t NEED = (XB_E + WQ_E + WO_E + 3 * XB_E) * 2;  // ~101 MB

  if (ws_size >= NEED) {
    u16* xb  = (u16*)d_ws;
    u16* wqb = xb + XB_E;
    u16* wob = wqb + WQ_E;
    u16* qb  = wob + WO_E;
    u16* kb  = qb + XB_E;
    u16* vb  = kb + XB_E;
    u16* ctx = xb;                 // xb dead after QKV GEMM; reuse for ctx

    cvt_kernel<<<dim3(XB_E / 1024), 256, 0, stream>>>(x, xb);
    cvt_kernel<<<dim3(WQ_E / 1024), 256, 0, stream>>>(Wqkv, wqb);
    cvt_kernel<<<dim3(WO_E / 1024), 256, 0, stream>>>(Wout, wob);
    gemm_bt<4096, 6144, 2048, 1, true, true><<<dim3(48, 32), 256, 0, stream>>>(
        xb, wqb, bqkv, qb, kb, vb);
    attn_kernel<<<dim3(16, 32), 256, 0, stream>>>(qb, kb, vb, ctx);
    gemm_bt<4096, 2048, 2048, 0, true, true><<<dim3(16, 32), 256, 0, stream>>>(
        ctx, wob, bout, out, nullptr, nullptr);
  } else {
    // fallback: 48 MiB ws, fused fp32->bf16 staging in GEMMs, ctx in d_out
    u16* qb = (u16*)d_ws;
    u16* kb = qb + XB_E;
    u16* vb = kb + XB_E;
    u16* ctx = (u16*)d_out;
    float* tmpo = (float*)d_ws;   // over dead qb/kb at out-proj time

    gemm_bt<4096, 6144, 2048, 1, false, false><<<dim3(48, 32), 256, 0, stream>>>(
        x, Wqkv, bqkv, qb, kb, vb);
    attn_kernel<<<dim3(16, 32), 256, 0, stream>>>(qb, kb, vb, ctx);
    gemm_bt<4096, 2048, 2048, 0, true, false><<<dim3(16, 32), 256, 0, stream>>>(
        ctx, Wout, bout, tmpo, nullptr, nullptr);
    hipMemcpyAsync(out, tmpo, (size_t)out_size * sizeof(float),
                   hipMemcpyDeviceToDevice, stream);
  }
}